// Round 12
// baseline (5172.854 us; speedup 1.0000x reference)
//
#include <hip/hip_runtime.h>

#define BB 128
#define TT 1024
#define INP 54
#define HUM 64
#define NPSI 96540
#define OFF_BH 65536
#define OFF_WIH 65792
#define OFF_C 79616
#define OFF_D 96000
#define OUT_MU 8388608
#define OUT_LS 8390656
#define OUT_HL 8392704

typedef unsigned int u32;
typedef unsigned short u16;
typedef _Float16 h2 __attribute__((ext_vector_type(2)));

__device__ __forceinline__ u32 pk(float a, float b) {
    h2 v; v.x = (_Float16)a; v.y = (_Float16)b;
    return __builtin_bit_cast(u32, v);
}
__device__ __forceinline__ float f16tof(u16 v) {
    return (float)__builtin_bit_cast(_Float16, v);
}
__device__ __forceinline__ u16 ftof16(float v) {
    return __builtin_bit_cast(u16, (_Float16)v);
}
__device__ __forceinline__ float lo16f(u32 v) { return f16tof((u16)(v & 0xffffu)); }
__device__ __forceinline__ float hi16f(u32 v) { return f16tof((u16)(v >> 16)); }
__device__ __forceinline__ h2 bch2(u32 a) { return __builtin_bit_cast(h2, a); }
__device__ __forceinline__ float fd2(u32 a, u32 b, float c) {
#if __has_builtin(__builtin_amdgcn_fdot2)
    return __builtin_amdgcn_fdot2(bch2(a), bch2(b), c, false);
#else
    return c + lo16f(a) * lo16f(b) + hi16f(a) * hi16f(b);
#endif
}
__device__ __forceinline__ float fsig(float x) { return 1.f / (1.f + __expf(-x)); }
__device__ __forceinline__ float ftanh(float x) { float e = __expf(2.f * x); return 1.f - 2.f / (e + 1.f); }

__device__ __forceinline__ float qred(float v) {
#if __has_builtin(__builtin_amdgcn_mov_dpp)
    int x = __builtin_bit_cast(int, v);
    v += __builtin_bit_cast(float, __builtin_amdgcn_mov_dpp(x, 0xB1, 0xF, 0xF, true)); // [1,0,3,2]
    x = __builtin_bit_cast(int, v);
    v += __builtin_bit_cast(float, __builtin_amdgcn_mov_dpp(x, 0x4E, 0xF, 0xF, true)); // [2,3,0,1]
    return v;
#else
    v += __shfl_xor(v, 1); v += __shfl_xor(v, 2);
    return v;
#endif
}

// ------------------------------------------------------- x-side projections --
__global__ __launch_bounds__(768, 3) void gemm_x_kernel(
    const float* __restrict__ inp, const float* __restrict__ W0,
    const u16* __restrict__ psi16, int mode, int t0, int len, int ct, int nt,
    u16* __restrict__ gout)
{
    const int tid = threadIdx.x;
    const int b = blockIdx.x / nt, tc = blockIdx.x % nt;
    const int gr = tid;
    float w[INP];
    if (mode == 0 || gr < 512) {
        const float* wsrc = W0 + (size_t)gr * INP;
#pragma unroll
        for (int c = 0; c < INP; ++c) w[c] = wsrc[c];
    } else {
        const u16* wsrc = psi16 + (size_t)b * NPSI + OFF_WIH + (size_t)(gr - 512) * INP;
#pragma unroll
        for (int c = 0; c < INP; ++c) w[c] = f16tof(wsrc[c]);
    }
    const int tb = tc * 128;
    const int te = (tb + 128 < len) ? tb + 128 : len;
    for (int tl = tb; tl < te; ++tl) {
        const float* xr = inp + ((size_t)b * TT + t0 + tl) * INP;
        float a = 0.f;
#pragma unroll
        for (int c = 0; c < INP; ++c) a = __builtin_fmaf(xr[c], w[c], a);
        gout[((size_t)b * ct + tl) * 768 + gr] = ftof16(a);
    }
}

// ---------------------------------------------------------------- encoder ---
// 1024 thr = 16 waves = exactly 4 waves/SIMD (waves_per_eu(4,4) -> 128-reg
// budget). Thread (l=tid&3, g=tid>>2): 64-h segment l of gate rows r=g,
// z=256+g, n=512+g -> 96 weight u32, all in arch VGPRs. dot2 + DPP qred.
__global__ __launch_bounds__(1024) __attribute__((amdgpu_waves_per_eu(4, 4)))
void enc_scan_kernel(
    const u16* __restrict__ gi, int t0, int len, int ct,
    const float* __restrict__ Whh, const float* __restrict__ bih,
    const float* __restrict__ bhh, float* __restrict__ hcarry)
{
    __shared__ __align__(16) u32 hpp[2][144];
    __shared__ __align__(16) u32 gxs32[2][3072];   // 8 steps x 768 u16
    const int tid = threadIdx.x, b = blockIdx.x;
    const int l = tid & 3, g = tid >> 2;

    u32 wr[32], wz[32], wn[32];
    {
        const float* pr = Whh + (size_t)g * 256 + 64 * l;
        const float* pz = Whh + (size_t)(256 + g) * 256 + 64 * l;
        const float* pn = Whh + (size_t)(512 + g) * 256 + 64 * l;
#pragma unroll
        for (int c = 0; c < 32; ++c) {
            wr[c] = pk(pr[2 * c], pr[2 * c + 1]);
            wz[c] = pk(pz[2 * c], pz[2 * c + 1]);
            wn[c] = pk(pn[2 * c], pn[2 * c + 1]);
        }
    }
    const float brb = bih[g] + bhh[g];
    const float bzb = bih[256 + g] + bhh[256 + g];
    const float bib = bih[512 + g];
    const float bhb = bhh[512 + g];
    float hc = 0.f;
    if (t0 > 0) hc = hcarry[(size_t)b * 256 + g];
    if (tid < 128) {
        u32 hv = 0u;
        if (t0 > 0) hv = pk(hcarry[(size_t)b * 256 + 2 * tid], hcarry[(size_t)b * 256 + 2 * tid + 1]);
        hpp[0][36 * (tid >> 5) + (tid & 31)] = hv;
    }
    const u32* gb32 = (const u32*)(gi + (size_t)b * ct * 768);
    {
        const int steps0 = (len < 8) ? len : 8;
#pragma unroll
        for (int k = 0; k < 3; ++k) {
            const int f = k * 1024 + tid;
            if (f < 384 * steps0) gxs32[0][f] = gb32[f];
        }
    }
    __syncthreads();

    int buf = 0;
    for (int cb = 0; cb < len; cb += 8) {
        const int steps = (len - cb < 8) ? (len - cb) : 8;
        const int nsteps = (len - cb - 8 < 8) ? (len - cb - 8) : 8;
        u32 stg[3];
        if (nsteps > 0) {
            const u32* gsrc = gb32 + (size_t)(cb + 8) * 384;
#pragma unroll
            for (int k = 0; k < 3; ++k) {
                const int f = k * 1024 + tid;
                if (f < 384 * nsteps) stg[k] = gsrc[f];
            }
        }
        for (int st = 0; st < steps; ++st) {
            const int tl = cb + st;
            const int p = tl & 1;
            float ar = 0, az = 0, ah = 0;
            const uint4* hq = (const uint4*)hpp[p];
#pragma unroll
            for (int cc = 0; cc < 8; ++cc) {
                uint4 q = hq[9 * l + cc];
                u32 qa[4] = {q.x, q.y, q.z, q.w};
#pragma unroll
                for (int u = 0; u < 4; ++u) {
                    const int c = cc * 4 + u;
                    ar = fd2(wr[c], qa[u], ar);
                    az = fd2(wz[c], qa[u], az);
                    ah = fd2(wn[c], qa[u], ah);
                }
            }
            ar = qred(ar); az = qred(az); ah = qred(ah);
            if (l == 0) {
                const u16* gx16 = (const u16*)gxs32[buf];
                const float c0 = f16tof(gx16[st * 768 + g]);
                const float c1 = f16tof(gx16[st * 768 + 256 + g]);
                const float c2 = f16tof(gx16[st * 768 + 512 + g]);
                float r = fsig(ar + c0 + brb);
                float z = fsig(az + c1 + bzb);
                float nn = ftanh(c2 + bib + r * (ah + bhb));
                float hn = (1.f - z) * nn + z * hc;
                hc = hn;
                float ho = __shfl_xor(hn, 4);
                if (!(g & 1)) {
                    const int gp = g >> 1;
                    hpp[p ^ 1][36 * (gp >> 5) + (gp & 31)] = pk(hn, ho);
                }
            }
            __syncthreads();
        }
        if (nsteps > 0) {
#pragma unroll
            for (int k = 0; k < 3; ++k) {
                const int f = k * 1024 + tid;
                if (f < 384 * nsteps) gxs32[buf ^ 1][f] = stg[k];
            }
        }
        __syncthreads();
        buf ^= 1;
    }
    if (l == 0) hcarry[(size_t)b * 256 + g] = hc;
}

// ----------------------------------------------------------------- latent ---
__global__ __launch_bounds__(256) void latent_kernel(
    const float* __restrict__ henc, const float* __restrict__ eps,
    const float* __restrict__ to_mu, const float* __restrict__ to_ls,
    const float* __restrict__ W1, const float* __restrict__ b1,
    const float* __restrict__ W2, const float* __restrict__ b2,
    float* __restrict__ psi2, float* __restrict__ out)
{
    __shared__ float h[256], zz[16], p1[256];
    const int tid = threadIdx.x, b = blockIdx.x;
    h[tid] = henc[(size_t)b * 256 + tid];
    __syncthreads();
    if (tid < 16) {
        float m = 0, s = 0;
        for (int k = 0; k < 256; ++k) {
            m += h[k] * to_mu[tid * 256 + k];
            s += h[k] * to_ls[tid * 256 + k];
        }
        out[OUT_MU + b * 16 + tid] = m;
        out[OUT_LS + b * 16 + tid] = s;
        zz[tid] = m + eps[b * 16 + tid] * __expf(s);
    }
    __syncthreads();
    {
        float a = b1[tid];
        for (int k = 0; k < 16; ++k) a += zz[k] * W1[tid * 16 + k];
        p1[tid] = ftanh(a);
    }
    __syncthreads();
    if (tid < 32) {
        float a = b2[tid];
        for (int k = 0; k < 256; ++k) a += p1[k] * W2[tid * 256 + k];
        psi2[b * 32 + tid] = a;
    }
}

// ------------------------------------------------------------------- psi3 ---
__global__ __launch_bounds__(256) void psi3_kernel(
    const float* __restrict__ psi2, const float* __restrict__ W3,
    const float* __restrict__ b3, u16* __restrict__ psi16)
{
    __shared__ float sp2[128 * 32];
    __shared__ float w3t[256 * 33];
    const int tid = threadIdx.x;
    const int n0 = blockIdx.x * 256;
    for (int idx = tid; idx < 4096; idx += 256) sp2[idx] = psi2[idx];
    for (int idx = tid; idx < 8192; idx += 256) {
        int row = idx >> 5, k = idx & 31;
        int n = n0 + row;
        w3t[row * 33 + k] = (n < NPSI) ? W3[(size_t)n * 32 + k] : 0.f;
    }
    __syncthreads();
    const int n = n0 + tid;
    if (n < NPSI) {
        float w[32];
#pragma unroll
        for (int k = 0; k < 32; ++k) w[k] = w3t[tid * 33 + k];
        const float bv = b3[n];
        for (int bi = 0; bi < 128; ++bi) {
            float a = bv;
#pragma unroll
            for (int k = 0; k < 32; ++k) a += sp2[bi * 32 + k] * w[k];
            psi16[(size_t)bi * NPSI + n] = ftof16(a);
        }
    }
}

// ----------------------- decoder scan (1024 thr, same geometry), hseq trace --
__global__ __launch_bounds__(1024) __attribute__((amdgpu_waves_per_eu(4, 4)))
void dec_scan_kernel(
    const u16* __restrict__ gx, int t0, int len, int ct,
    const float* __restrict__ state, const float* __restrict__ gWhh,
    const float* __restrict__ gbias, const u16* __restrict__ psi16,
    float* __restrict__ dcarry, u32* __restrict__ hseq, float* __restrict__ out)
{
    __shared__ __align__(16) u32 hpp[2][144];
    __shared__ __align__(16) u32 gxs32[2][3072];
    const int tid = threadIdx.x, b = blockIdx.x;
    const int l = tid & 3, g = tid >> 2;
    const u16* pc = psi16 + (size_t)b * NPSI;

    u32 wz[32], wrr[32], wp[32];
#pragma unroll
    for (int c = 0; c < 32; ++c) {
        const int h0 = 64 * l + 2 * c;
        wz[c]  = pk(gWhh[(size_t)h0 * 512 + g], gWhh[(size_t)(h0 + 1) * 512 + g]);
        wrr[c] = pk(gWhh[(size_t)h0 * 512 + 256 + g], gWhh[(size_t)(h0 + 1) * 512 + 256 + g]);
        wp[c]  = (u32)pc[(size_t)h0 * 256 + g] | ((u32)pc[(size_t)(h0 + 1) * 256 + g] << 16);
    }
    const float gzb = gbias[g];
    const float grb = gbias[256 + g];
    const float bhb = f16tof(pc[OFF_BH + g]);
    const float* hsrc = (t0 == 0) ? state : dcarry;
    float hc = hsrc[(size_t)b * 256 + g];
    if (tid < 128) hpp[0][36 * (tid >> 5) + (tid & 31)] =
        pk(hsrc[(size_t)b * 256 + 2 * tid], hsrc[(size_t)b * 256 + 2 * tid + 1]);
    const u32* gb32 = (const u32*)(gx + (size_t)b * ct * 768);
    {
        const int steps0 = (len < 8) ? len : 8;
#pragma unroll
        for (int k = 0; k < 3; ++k) {
            const int f = k * 1024 + tid;
            if (f < 384 * steps0) gxs32[0][f] = gb32[f];
        }
    }
    __syncthreads();

    u32* hsb = hseq + (size_t)b * TT * 128;
    int buf = 0;
    for (int cb = 0; cb < len; cb += 8) {
        const int steps = (len - cb < 8) ? (len - cb) : 8;
        const int nsteps = (len - cb - 8 < 8) ? (len - cb - 8) : 8;
        u32 stg[3];
        if (nsteps > 0) {
            const u32* gsrc = gb32 + (size_t)(cb + 8) * 384;
#pragma unroll
            for (int k = 0; k < 3; ++k) {
                const int f = k * 1024 + tid;
                if (f < 384 * nsteps) stg[k] = gsrc[f];
            }
        }
        for (int st = 0; st < steps; ++st) {
            const int tl = cb + st;
            const int p = tl & 1;
            float az = 0, ar = 0, ap = 0;
            const uint4* hq = (const uint4*)hpp[p];
#pragma unroll
            for (int cc = 0; cc < 8; ++cc) {
                uint4 q = hq[9 * l + cc];
                u32 qa[4] = {q.x, q.y, q.z, q.w};
#pragma unroll
                for (int u = 0; u < 4; ++u) {
                    const int c = cc * 4 + u;
                    az = fd2(wz[c], qa[u], az);
                    ar = fd2(wrr[c], qa[u], ar);
                    ap = fd2(wp[c], qa[u], ap);
                }
            }
            az = qred(az); ar = qred(ar); ap = qred(ap);
            if (l == 0) {
                const u16* gx16 = (const u16*)gxs32[buf];
                const float c0 = f16tof(gx16[st * 768 + g]);
                const float c1 = f16tof(gx16[st * 768 + 256 + g]);
                const float c2 = f16tof(gx16[st * 768 + 512 + g]);
                float zt = fsig(az + c0 + gzb);
                float rt = fsig(ar + c1 + grb);
                float eta = ftanh(c2 + rt * ftanh(ap + bhb));
                float hn = zt * hc + (1.f - zt) * eta;
                hc = hn;
                float ho = __shfl_xor(hn, 4);
                if (!(g & 1)) {
                    const int gp = g >> 1;
                    u32 hv = pk(hn, ho);
                    hpp[p ^ 1][36 * (gp >> 5) + (gp & 31)] = hv;
                    hsb[(size_t)(t0 + tl) * 128 + gp] = hv;
                }
            }
            __syncthreads();
        }
        if (nsteps > 0) {
#pragma unroll
            for (int k = 0; k < 3; ++k) {
                const int f = k * 1024 + tid;
                if (f < 384 * nsteps) gxs32[buf ^ 1][f] = stg[k];
            }
        }
        __syncthreads();
        buf ^= 1;
    }
    if (l == 0) {
        dcarry[(size_t)b * 256 + g] = hc;
        if (t0 + len == TT) out[OUT_HL + (size_t)b * 256 + g] = hc;
    }
}

// ------------------------------------------------------------------- yhat ---
#define YT 32
__global__ __launch_bounds__(256) void yhat_kernel(
    const u32* __restrict__ hseq, const u16* __restrict__ psi16,
    float* __restrict__ out)
{
    __shared__ float part[2][YT][64];
    const int tid = threadIdx.x;
    const int b = blockIdx.x >> 5, tile = blockIdx.x & 31;
    const int o = tid & 63, s = (tid >> 6) & 1, tq = tid >> 7;
    const u16* pc = psi16 + (size_t)b * NPSI;
    u32 cpr[64];
#pragma unroll
    for (int i = 0; i < 64; ++i) {
        const int gp = s * 64 + i;
        cpr[i] = (u32)pc[OFF_C + (size_t)(2 * gp) * 64 + o]
               | ((u32)pc[OFF_C + (size_t)(2 * gp + 1) * 64 + o] << 16);
    }
    const int t0 = tile * YT;
    for (int th = 0; th < YT / 2; ++th) {
        const int tl = tq * (YT / 2) + th;
        const uint4* h4 = (const uint4*)(hseq + ((size_t)b * TT + t0 + tl) * 128 + s * 64);
        float a = 0.f;
#pragma unroll
        for (int gc = 0; gc < 16; ++gc) {
            uint4 q = h4[gc];
            a = fd2(q.x, cpr[gc * 4 + 0], a);
            a = fd2(q.y, cpr[gc * 4 + 1], a);
            a = fd2(q.z, cpr[gc * 4 + 2], a);
            a = fd2(q.w, cpr[gc * 4 + 3], a);
        }
        part[s][tl][o] = a;
    }
    __syncthreads();
    for (int i = 0; i < 8; ++i) {
        const int flat = i * 256 + tid;
        const int tl = flat >> 6, o2 = flat & 63;
        out[((size_t)b * TT + t0 + tl) * HUM + o2] = part[0][tl][o2] + part[1][tl][o2];
    }
}

// ------------------------------------------------- x add + D_p einsum fixup --
__global__ __launch_bounds__(256) void post_kernel(
    const float* __restrict__ inp, const u16* __restrict__ psi16,
    float* __restrict__ out)
{
    __shared__ float xs[128][55];
    __shared__ float ds[INP][10];
    const int tid = threadIdx.x;
    const int b = blockIdx.x >> 3, tile = blockIdx.x & 7;
    const int t0 = tile * 128;
    const u16* pc = psi16 + (size_t)b * NPSI;
    for (int idx = tid; idx < 540; idx += 256)
        ds[idx / 10][idx % 10] = f16tof(pc[OFF_D + idx]);
    for (int idx = tid; idx < 128 * INP; idx += 256) {
        const int t = idx / INP, d = idx % INP;
        xs[t][d] = inp[((size_t)b * TT + t0 + t) * INP + d];
    }
    __syncthreads();
    for (int i = 0; i < 32; ++i) {
        const int flat = i * 256 + tid;
        const int t = flat >> 6, o = flat & 63;
        const size_t oi = ((size_t)b * TT + t0 + t) * HUM + o;
        float y = out[oi];
        if (o < INP) y += xs[t][o];
        else {
            float acc = 0.f;
            for (int d = 0; d < INP; ++d) acc += xs[t][d] * ds[d][o - INP];
            y += acc;
        }
        out[oi] = y;
    }
}

// ----------------------------------------------------------------- launch ---
extern "C" void kernel_launch(void* const* d_in, const int* in_sizes, int n_in,
                              void* d_out, int out_size, void* d_ws, size_t ws_size,
                              hipStream_t stream)
{
    const float* inputs = (const float*)d_in[0];
    const float* state  = (const float*)d_in[1];
    const float* eps    = (const float*)d_in[2];
    const float* eWih   = (const float*)d_in[3];
    const float* eWhh   = (const float*)d_in[4];
    const float* ebih   = (const float*)d_in[5];
    const float* ebhh   = (const float*)d_in[6];
    const float* to_mu  = (const float*)d_in[7];
    const float* to_ls  = (const float*)d_in[8];
    const float* W1     = (const float*)d_in[9];
    const float* b1     = (const float*)d_in[10];
    const float* W2     = (const float*)d_in[11];
    const float* b2     = (const float*)d_in[12];
    const float* W3     = (const float*)d_in[13];
    const float* b3     = (const float*)d_in[14];
    const float* gWih   = (const float*)d_in[15];
    const float* gWhh   = (const float*)d_in[16];
    const float* gbias  = (const float*)d_in[17];
    float* out = (float*)d_out;
    float* ws  = (float*)d_ws;

    float* henc   = ws;                          // 32768 f
    float* psi2   = ws + 32768;                  // 4096 f
    float* dcarry = ws + 36864;                  // 32768 f
    u16*   psi16  = (u16*)(ws + 69632);          // 24,714,240 B -> ends 6,248,192 f
    u32*   hseq   = (u32*)(ws + 6248192);        // 16,777,216 u32 -> ends 23,025,408 f
    u16*   gbuf   = (u16*)(ws + 23025408);
    const size_t used = (size_t)23025408 * 4;
    size_t avail = (ws_size > used + 4096) ? (ws_size - used - 4096) : 0;
    int ct = (int)(avail / ((size_t)BB * 768 * 2));
    if (ct > TT) ct = TT;
    if (ct < 1) ct = 1;

    for (int t0 = 0; t0 < TT; t0 += ct) {
        const int len = (TT - t0 < ct) ? (TT - t0) : ct;
        const int nt = (len + 127) / 128;
        gemm_x_kernel<<<BB * nt, 768, 0, stream>>>(inputs, eWih, psi16, 0, t0, len, ct, nt, gbuf);
        enc_scan_kernel<<<BB, 1024, 0, stream>>>(gbuf, t0, len, ct, eWhh, ebih, ebhh, henc);
    }
    latent_kernel<<<BB, 256, 0, stream>>>(henc, eps, to_mu, to_ls, W1, b1, W2, b2, psi2, out);
    psi3_kernel<<<(NPSI + 255) / 256, 256, 0, stream>>>(psi2, W3, b3, psi16);
    for (int t0 = 0; t0 < TT; t0 += ct) {
        const int len = (TT - t0 < ct) ? (TT - t0) : ct;
        const int nt = (len + 127) / 128;
        gemm_x_kernel<<<BB * nt, 768, 0, stream>>>(inputs, gWih, psi16, 1, t0, len, ct, nt, gbuf);
        dec_scan_kernel<<<BB, 1024, 0, stream>>>(gbuf, t0, len, ct, state, gWhh, gbias, psi16,
                                                 dcarry, hseq, out);
    }
    yhat_kernel<<<BB * 32, 256, 0, stream>>>(hseq, psi16, out);
    post_kernel<<<BB * 8, 256, 0, stream>>>(inputs, psi16, out);
}

// Round 13
// 4531.055 us; speedup vs baseline: 1.1416x; 1.1416x over previous
//
#include <hip/hip_runtime.h>

#define BB 128
#define TT 1024
#define INP 54
#define HUM 64
#define NPSI 96540
#define OFF_BH 65536
#define OFF_WIH 65792
#define OFF_C 79616
#define OFF_D 96000
#define OUT_MU 8388608
#define OUT_LS 8390656
#define OUT_HL 8392704

typedef unsigned int u32;
typedef unsigned short u16;
typedef _Float16 h2 __attribute__((ext_vector_type(2)));

__device__ __forceinline__ u32 pk(float a, float b) {
    h2 v; v.x = (_Float16)a; v.y = (_Float16)b;
    return __builtin_bit_cast(u32, v);
}
__device__ __forceinline__ float f16tof(u16 v) {
    return (float)__builtin_bit_cast(_Float16, v);
}
__device__ __forceinline__ u16 ftof16(float v) {
    return __builtin_bit_cast(u16, (_Float16)v);
}
__device__ __forceinline__ float lo16f(u32 v) { return f16tof((u16)(v & 0xffffu)); }
__device__ __forceinline__ float hi16f(u32 v) { return f16tof((u16)(v >> 16)); }
__device__ __forceinline__ h2 bch2(u32 a) { return __builtin_bit_cast(h2, a); }
// v_dot2_f32_f16: 2 f16 MACs + f32 accumulate in ONE instruction
__device__ __forceinline__ float fd2(u32 a, u32 b, float c) {
#if __has_builtin(__builtin_amdgcn_fdot2)
    return __builtin_amdgcn_fdot2(bch2(a), bch2(b), c, false);
#else
    return c + lo16f(a) * lo16f(b) + hi16f(a) * hi16f(b);
#endif
}
__device__ __forceinline__ float fsig(float x) { return 1.f / (1.f + __expf(-x)); }
__device__ __forceinline__ float ftanh(float x) { float e = __expf(2.f * x); return 1.f - 2.f / (e + 1.f); }

__device__ __forceinline__ float qred(float v) {
#if __has_builtin(__builtin_amdgcn_mov_dpp)
    int x = __builtin_bit_cast(int, v);
    v += __builtin_bit_cast(float, __builtin_amdgcn_mov_dpp(x, 0xB1, 0xF, 0xF, true)); // [1,0,3,2]
    x = __builtin_bit_cast(int, v);
    v += __builtin_bit_cast(float, __builtin_amdgcn_mov_dpp(x, 0x4E, 0xF, 0xF, true)); // [2,3,0,1]
    return v;
#else
    v += __shfl_xor(v, 1); v += __shfl_xor(v, 2);
    return v;
#endif
}

// ------------------------------------------------------- x-side projections --
__global__ __launch_bounds__(768, 3) void gemm_x_kernel(
    const float* __restrict__ inp, const float* __restrict__ W0,
    const u16* __restrict__ psi16, int mode, int t0, int len, int ct, int nt,
    u16* __restrict__ gout)
{
    const int tid = threadIdx.x;
    const int b = blockIdx.x / nt, tc = blockIdx.x % nt;
    const int gr = tid;
    float w[INP];
    if (mode == 0 || gr < 512) {
        const float* wsrc = W0 + (size_t)gr * INP;
#pragma unroll
        for (int c = 0; c < INP; ++c) w[c] = wsrc[c];
    } else {
        const u16* wsrc = psi16 + (size_t)b * NPSI + OFF_WIH + (size_t)(gr - 512) * INP;
#pragma unroll
        for (int c = 0; c < INP; ++c) w[c] = f16tof(wsrc[c]);
    }
    const int tb = tc * 128;
    const int te = (tb + 128 < len) ? tb + 128 : len;
    for (int tl = tb; tl < te; ++tl) {
        const float* xr = inp + ((size_t)b * TT + t0 + tl) * INP;
        float a = 0.f;
#pragma unroll
        for (int c = 0; c < INP; ++c) a = __builtin_fmaf(xr[c], w[c], a);
        gout[((size_t)b * ct + tl) * 768 + gr] = ftof16(a);
    }
}

// ---------------------------------------------------------------- encoder ---
// r8's proven enc: 512 thr, l=tid&3 (64-h seg), g=tid>>2, rows j0=2g, j1=2g+1;
// dot2 matvec, per-step u32 global prefetch of gx.
__global__ __launch_bounds__(512) __attribute__((amdgpu_waves_per_eu(2, 2)))
void enc_scan_kernel(
    const u16* __restrict__ gi, int t0, int len, int ct,
    const float* __restrict__ Whh, const float* __restrict__ bih,
    const float* __restrict__ bhh, float* __restrict__ hcarry)
{
    __shared__ __align__(16) u32 hpp[2][144];
    const int tid = threadIdx.x, b = blockIdx.x;
    const int l = tid & 3, g = tid >> 2;
    const int j0 = 2 * g, j1 = 2 * g + 1;

    u32 wr0[32], wz0[32], wn0[32], wr1[32], wz1[32], wn1[32];
    {
        const float* pr0 = Whh + (size_t)j0 * 256 + 64 * l;
        const float* pz0 = Whh + (size_t)(256 + j0) * 256 + 64 * l;
        const float* pn0 = Whh + (size_t)(512 + j0) * 256 + 64 * l;
        const float* pr1 = Whh + (size_t)j1 * 256 + 64 * l;
        const float* pz1 = Whh + (size_t)(256 + j1) * 256 + 64 * l;
        const float* pn1 = Whh + (size_t)(512 + j1) * 256 + 64 * l;
#pragma unroll
        for (int c = 0; c < 32; ++c) {
            wr0[c] = pk(pr0[2 * c], pr0[2 * c + 1]);
            wz0[c] = pk(pz0[2 * c], pz0[2 * c + 1]);
            wn0[c] = pk(pn0[2 * c], pn0[2 * c + 1]);
            wr1[c] = pk(pr1[2 * c], pr1[2 * c + 1]);
            wz1[c] = pk(pz1[2 * c], pz1[2 * c + 1]);
            wn1[c] = pk(pn1[2 * c], pn1[2 * c + 1]);
        }
    }
    const float brb0 = bih[j0] + bhh[j0],             brb1 = bih[j1] + bhh[j1];
    const float bzb0 = bih[256 + j0] + bhh[256 + j0], bzb1 = bih[256 + j1] + bhh[256 + j1];
    const float bib0 = bih[512 + j0],                 bib1 = bih[512 + j1];
    const float bhb0 = bhh[512 + j0],                 bhb1 = bhh[512 + j1];
    float hc0 = 0.f, hc1 = 0.f;
    if (t0 > 0) { hc0 = hcarry[(size_t)b * 256 + j0]; hc1 = hcarry[(size_t)b * 256 + j1]; }
    if (tid < 128) {
        u32 hv = 0u;
        if (t0 > 0) hv = pk(hcarry[(size_t)b * 256 + 2 * tid], hcarry[(size_t)b * 256 + 2 * tid + 1]);
        hpp[0][36 * (tid >> 5) + (tid & 31)] = hv;
    }
    __syncthreads();

    const u16* gbase = gi + (size_t)b * ct * 768;
    u32 c0 = *(const u32*)(gbase + 2 * g);
    u32 c1 = *(const u32*)(gbase + 256 + 2 * g);
    u32 c2 = *(const u32*)(gbase + 512 + 2 * g);

    for (int tl = 0; tl < len; ++tl) {
        const int p = tl & 1;
        u32 n0 = 0, n1 = 0, n2 = 0;
        if (tl + 1 < len) {
            const u16* gn = gbase + (size_t)(tl + 1) * 768;
            n0 = *(const u32*)(gn + 2 * g);
            n1 = *(const u32*)(gn + 256 + 2 * g);
            n2 = *(const u32*)(gn + 512 + 2 * g);
        }
        float ar0 = 0, az0 = 0, ah0 = 0, ar1 = 0, az1 = 0, ah1 = 0;
        const uint4* hq = (const uint4*)hpp[p];
#pragma unroll
        for (int cc = 0; cc < 8; ++cc) {
            uint4 q = hq[9 * l + cc];
            u32 qa[4] = {q.x, q.y, q.z, q.w};
#pragma unroll
            for (int u = 0; u < 4; ++u) {
                const int c = cc * 4 + u;
                ar0 = fd2(wr0[c], qa[u], ar0);
                az0 = fd2(wz0[c], qa[u], az0);
                ah0 = fd2(wn0[c], qa[u], ah0);
                ar1 = fd2(wr1[c], qa[u], ar1);
                az1 = fd2(wz1[c], qa[u], az1);
                ah1 = fd2(wn1[c], qa[u], ah1);
            }
        }
        ar0 = qred(ar0); az0 = qred(az0); ah0 = qred(ah0);
        ar1 = qred(ar1); az1 = qred(az1); ah1 = qred(ah1);
        {
            float r0 = fsig(ar0 + lo16f(c0) + brb0);
            float z0 = fsig(az0 + lo16f(c1) + bzb0);
            float nn0 = ftanh(lo16f(c2) + bib0 + r0 * (ah0 + bhb0));
            float hn0 = (1.f - z0) * nn0 + z0 * hc0;
            float r1 = fsig(ar1 + hi16f(c0) + brb1);
            float z1 = fsig(az1 + hi16f(c1) + bzb1);
            float nn1 = ftanh(hi16f(c2) + bib1 + r1 * (ah1 + bhb1));
            float hn1 = (1.f - z1) * nn1 + z1 * hc1;
            hc0 = hn0; hc1 = hn1;
            if (l == 0) hpp[p ^ 1][36 * (g >> 5) + (g & 31)] = pk(hn0, hn1);
        }
        c0 = n0; c1 = n1; c2 = n2;
        __syncthreads();
    }
    if (l == 0) {
        hcarry[(size_t)b * 256 + j0] = hc0;
        hcarry[(size_t)b * 256 + j1] = hc1;
    }
}

// ----------------------------------------------------------------- latent ---
__global__ __launch_bounds__(256) void latent_kernel(
    const float* __restrict__ henc, const float* __restrict__ eps,
    const float* __restrict__ to_mu, const float* __restrict__ to_ls,
    const float* __restrict__ W1, const float* __restrict__ b1,
    const float* __restrict__ W2, const float* __restrict__ b2,
    float* __restrict__ psi2, float* __restrict__ out)
{
    __shared__ float h[256], zz[16], p1[256];
    const int tid = threadIdx.x, b = blockIdx.x;
    h[tid] = henc[(size_t)b * 256 + tid];
    __syncthreads();
    if (tid < 16) {
        float m = 0, s = 0;
        for (int k = 0; k < 256; ++k) {
            m += h[k] * to_mu[tid * 256 + k];
            s += h[k] * to_ls[tid * 256 + k];
        }
        out[OUT_MU + b * 16 + tid] = m;
        out[OUT_LS + b * 16 + tid] = s;
        zz[tid] = m + eps[b * 16 + tid] * __expf(s);
    }
    __syncthreads();
    {
        float a = b1[tid];
        for (int k = 0; k < 16; ++k) a += zz[k] * W1[tid * 16 + k];
        p1[tid] = ftanh(a);
    }
    __syncthreads();
    if (tid < 32) {
        float a = b2[tid];
        for (int k = 0; k < 256; ++k) a += p1[k] * W2[tid * 256 + k];
        psi2[b * 32 + tid] = a;
    }
}

// ------------------------------------------------------------------- psi3 ---
__global__ __launch_bounds__(256) void psi3_kernel(
    const float* __restrict__ psi2, const float* __restrict__ W3,
    const float* __restrict__ b3, u16* __restrict__ psi16)
{
    __shared__ float sp2[128 * 32];
    __shared__ float w3t[256 * 33];
    const int tid = threadIdx.x;
    const int n0 = blockIdx.x * 256;
    for (int idx = tid; idx < 4096; idx += 256) sp2[idx] = psi2[idx];
    for (int idx = tid; idx < 8192; idx += 256) {
        int row = idx >> 5, k = idx & 31;
        int n = n0 + row;
        w3t[row * 33 + k] = (n < NPSI) ? W3[(size_t)n * 32 + k] : 0.f;
    }
    __syncthreads();
    const int n = n0 + tid;
    if (n < NPSI) {
        float w[32];
#pragma unroll
        for (int k = 0; k < 32; ++k) w[k] = w3t[tid * 33 + k];
        const float bv = b3[n];
        for (int bi = 0; bi < 128; ++bi) {
            float a = bv;
#pragma unroll
            for (int k = 0; k < 32; ++k) a += sp2[bi * 32 + k] * w[k];
            psi16[(size_t)bi * NPSI + n] = ftof16(a);
        }
    }
}

// ------------------- decoder scan (r11: dot2 + staged gx + hseq, no yhat) ---
__global__ __launch_bounds__(512) __attribute__((amdgpu_waves_per_eu(2, 2)))
void dec_scan_kernel(
    const u16* __restrict__ gx, int t0, int len, int ct,
    const float* __restrict__ state, const float* __restrict__ gWhh,
    const float* __restrict__ gbias, const u16* __restrict__ psi16,
    float* __restrict__ dcarry, u32* __restrict__ hseq, float* __restrict__ out)
{
    __shared__ __align__(16) u32 hpp[2][144];
    __shared__ __align__(16) u32 gxs32[2][3072];
    const int tid = threadIdx.x, b = blockIdx.x;
    const int l = tid & 3, g = tid >> 2;
    const int j0 = 2 * g, j1 = 2 * g + 1;
    const u16* pc = psi16 + (size_t)b * NPSI;

    u32 wz0[32], wr0[32], wp0[32], wz1[32], wr1[32], wp1[32];
#pragma unroll
    for (int c = 0; c < 32; ++c) {
        const int h0 = 64 * l + 2 * c;
        wz0[c] = pk(gWhh[(size_t)h0 * 512 + j0], gWhh[(size_t)(h0 + 1) * 512 + j0]);
        wr0[c] = pk(gWhh[(size_t)h0 * 512 + 256 + j0], gWhh[(size_t)(h0 + 1) * 512 + 256 + j0]);
        wp0[c] = (u32)pc[(size_t)h0 * 256 + j0] | ((u32)pc[(size_t)(h0 + 1) * 256 + j0] << 16);
        wz1[c] = pk(gWhh[(size_t)h0 * 512 + j1], gWhh[(size_t)(h0 + 1) * 512 + j1]);
        wr1[c] = pk(gWhh[(size_t)h0 * 512 + 256 + j1], gWhh[(size_t)(h0 + 1) * 512 + 256 + j1]);
        wp1[c] = (u32)pc[(size_t)h0 * 256 + j1] | ((u32)pc[(size_t)(h0 + 1) * 256 + j1] << 16);
    }
    const float gzb0 = gbias[j0], gzb1 = gbias[j1];
    const float grb0 = gbias[256 + j0], grb1 = gbias[256 + j1];
    const float bhb0 = f16tof(pc[OFF_BH + j0]), bhb1 = f16tof(pc[OFF_BH + j1]);
    const float* hsrc = (t0 == 0) ? state : dcarry;
    float hc0 = hsrc[(size_t)b * 256 + j0];
    float hc1 = hsrc[(size_t)b * 256 + j1];
    if (tid < 128) hpp[0][36 * (tid >> 5) + (tid & 31)] =
        pk(hsrc[(size_t)b * 256 + 2 * tid], hsrc[(size_t)b * 256 + 2 * tid + 1]);
    const u32* gb32 = (const u32*)(gx + (size_t)b * ct * 768);
    {
        const int steps0 = (len < 8) ? len : 8;
#pragma unroll
        for (int k = 0; k < 6; ++k) {
            const int f = k * 512 + tid;
            if (f < 384 * steps0) gxs32[0][f] = gb32[f];
        }
    }
    __syncthreads();

    u32* hsb = hseq + (size_t)b * TT * 128;
    int buf = 0;
    for (int cb = 0; cb < len; cb += 8) {
        const int steps = (len - cb < 8) ? (len - cb) : 8;
        const int nsteps = (len - cb - 8 < 8) ? (len - cb - 8) : 8;
        u32 stg[6];
        if (nsteps > 0) {
            const u32* gsrc = gb32 + (size_t)(cb + 8) * 384;
#pragma unroll
            for (int k = 0; k < 6; ++k) {
                const int f = k * 512 + tid;
                if (f < 384 * nsteps) stg[k] = gsrc[f];
            }
        }
        for (int st = 0; st < steps; ++st) {
            const int tl = cb + st;
            const int p = tl & 1;
            const u16* gx16 = (const u16*)gxs32[buf];
            const u32 c0 = *(const u32*)(gx16 + st * 768 + 2 * g);
            const u32 c1 = *(const u32*)(gx16 + st * 768 + 256 + 2 * g);
            const u32 c2 = *(const u32*)(gx16 + st * 768 + 512 + 2 * g);
            float az0 = 0, ar0 = 0, ap0 = 0, az1 = 0, ar1 = 0, ap1 = 0;
            const uint4* hq = (const uint4*)hpp[p];
#pragma unroll
            for (int cc = 0; cc < 8; ++cc) {
                uint4 q = hq[9 * l + cc];
                u32 qa[4] = {q.x, q.y, q.z, q.w};
#pragma unroll
                for (int u = 0; u < 4; ++u) {
                    const int c = cc * 4 + u;
                    az0 = fd2(wz0[c], qa[u], az0);
                    ar0 = fd2(wr0[c], qa[u], ar0);
                    ap0 = fd2(wp0[c], qa[u], ap0);
                    az1 = fd2(wz1[c], qa[u], az1);
                    ar1 = fd2(wr1[c], qa[u], ar1);
                    ap1 = fd2(wp1[c], qa[u], ap1);
                }
            }
            az0 = qred(az0); ar0 = qred(ar0); ap0 = qred(ap0);
            az1 = qred(az1); ar1 = qred(ar1); ap1 = qred(ap1);
            {
                float zt0 = fsig(az0 + lo16f(c0) + gzb0);
                float rt0 = fsig(ar0 + lo16f(c1) + grb0);
                float eta0 = ftanh(lo16f(c2) + rt0 * ftanh(ap0 + bhb0));
                float hn0 = zt0 * hc0 + (1.f - zt0) * eta0;
                float zt1 = fsig(az1 + hi16f(c0) + gzb1);
                float rt1 = fsig(ar1 + hi16f(c1) + grb1);
                float eta1 = ftanh(hi16f(c2) + rt1 * ftanh(ap1 + bhb1));
                float hn1 = zt1 * hc1 + (1.f - zt1) * eta1;
                hc0 = hn0; hc1 = hn1;
                if (l == 0) {
                    u32 hv = pk(hn0, hn1);
                    hpp[p ^ 1][36 * (g >> 5) + (g & 31)] = hv;
                    hsb[(size_t)(t0 + tl) * 128 + g] = hv;
                }
            }
            __syncthreads();
        }
        if (nsteps > 0) {
#pragma unroll
            for (int k = 0; k < 6; ++k) {
                const int f = k * 512 + tid;
                if (f < 384 * nsteps) gxs32[buf ^ 1][f] = stg[k];
            }
        }
        __syncthreads();
        buf ^= 1;
    }
    if (l == 0) {
        dcarry[(size_t)b * 256 + j0] = hc0;
        dcarry[(size_t)b * 256 + j1] = hc1;
        if (t0 + len == TT) {
            out[OUT_HL + (size_t)b * 256 + j0] = hc0;
            out[OUT_HL + (size_t)b * 256 + j1] = hc1;
        }
    }
}

// ------------------------------------------------------------------- yhat ---
#define YT 32
__global__ __launch_bounds__(256) void yhat_kernel(
    const u32* __restrict__ hseq, const u16* __restrict__ psi16,
    float* __restrict__ out)
{
    __shared__ float part[2][YT][64];
    const int tid = threadIdx.x;
    const int b = blockIdx.x >> 5, tile = blockIdx.x & 31;
    const int o = tid & 63, s = (tid >> 6) & 1, tq = tid >> 7;
    const u16* pc = psi16 + (size_t)b * NPSI;
    u32 cpr[64];
#pragma unroll
    for (int i = 0; i < 64; ++i) {
        const int gp = s * 64 + i;
        cpr[i] = (u32)pc[OFF_C + (size_t)(2 * gp) * 64 + o]
               | ((u32)pc[OFF_C + (size_t)(2 * gp + 1) * 64 + o] << 16);
    }
    const int t0 = tile * YT;
    for (int th = 0; th < YT / 2; ++th) {
        const int tl = tq * (YT / 2) + th;
        const uint4* h4 = (const uint4*)(hseq + ((size_t)b * TT + t0 + tl) * 128 + s * 64);
        float a = 0.f;
#pragma unroll
        for (int gc = 0; gc < 16; ++gc) {
            uint4 q = h4[gc];
            a = fd2(q.x, cpr[gc * 4 + 0], a);
            a = fd2(q.y, cpr[gc * 4 + 1], a);
            a = fd2(q.z, cpr[gc * 4 + 2], a);
            a = fd2(q.w, cpr[gc * 4 + 3], a);
        }
        part[s][tl][o] = a;
    }
    __syncthreads();
    for (int i = 0; i < 8; ++i) {
        const int flat = i * 256 + tid;
        const int tl = flat >> 6, o2 = flat & 63;
        out[((size_t)b * TT + t0 + tl) * HUM + o2] = part[0][tl][o2] + part[1][tl][o2];
    }
}

// ------------------------------------------------- x add + D_p einsum fixup --
__global__ __launch_bounds__(256) void post_kernel(
    const float* __restrict__ inp, const u16* __restrict__ psi16,
    float* __restrict__ out)
{
    __shared__ float xs[128][55];
    __shared__ float ds[INP][10];
    const int tid = threadIdx.x;
    const int b = blockIdx.x >> 3, tile = blockIdx.x & 7;
    const int t0 = tile * 128;
    const u16* pc = psi16 + (size_t)b * NPSI;
    for (int idx = tid; idx < 540; idx += 256)
        ds[idx / 10][idx % 10] = f16tof(pc[OFF_D + idx]);
    for (int idx = tid; idx < 128 * INP; idx += 256) {
        const int t = idx / INP, d = idx % INP;
        xs[t][d] = inp[((size_t)b * TT + t0 + t) * INP + d];
    }
    __syncthreads();
    for (int i = 0; i < 32; ++i) {
        const int flat = i * 256 + tid;
        const int t = flat >> 6, o = flat & 63;
        const size_t oi = ((size_t)b * TT + t0 + t) * HUM + o;
        float y = out[oi];
        if (o < INP) y += xs[t][o];
        else {
            float acc = 0.f;
            for (int d = 0; d < INP; ++d) acc += xs[t][d] * ds[d][o - INP];
            y += acc;
        }
        out[oi] = y;
    }
}

// ----------------------------------------------------------------- launch ---
extern "C" void kernel_launch(void* const* d_in, const int* in_sizes, int n_in,
                              void* d_out, int out_size, void* d_ws, size_t ws_size,
                              hipStream_t stream)
{
    const float* inputs = (const float*)d_in[0];
    const float* state  = (const float*)d_in[1];
    const float* eps    = (const float*)d_in[2];
    const float* eWih   = (const float*)d_in[3];
    const float* eWhh   = (const float*)d_in[4];
    const float* ebih   = (const float*)d_in[5];
    const float* ebhh   = (const float*)d_in[6];
    const float* to_mu  = (const float*)d_in[7];
    const float* to_ls  = (const float*)d_in[8];
    const float* W1     = (const float*)d_in[9];
    const float* b1     = (const float*)d_in[10];
    const float* W2     = (const float*)d_in[11];
    const float* b2     = (const float*)d_in[12];
    const float* W3     = (const float*)d_in[13];
    const float* b3     = (const float*)d_in[14];
    const float* gWih   = (const float*)d_in[15];
    const float* gWhh   = (const float*)d_in[16];
    const float* gbias  = (const float*)d_in[17];
    float* out = (float*)d_out;
    float* ws  = (float*)d_ws;

    float* henc   = ws;                          // 32768 f
    float* psi2   = ws + 32768;                  // 4096 f
    float* dcarry = ws + 36864;                  // 32768 f
    u16*   psi16  = (u16*)(ws + 69632);          // 24,714,240 B -> ends 6,248,192 f
    u32*   hseq   = (u32*)(ws + 6248192);        // 16,777,216 u32 -> ends 23,025,408 f
    u16*   gbuf   = (u16*)(ws + 23025408);
    const size_t used = (size_t)23025408 * 4;
    size_t avail = (ws_size > used + 4096) ? (ws_size - used - 4096) : 0;
    int ct = (int)(avail / ((size_t)BB * 768 * 2));
    if (ct > TT) ct = TT;
    if (ct < 1) ct = 1;

    for (int t0 = 0; t0 < TT; t0 += ct) {
        const int len = (TT - t0 < ct) ? (TT - t0) : ct;
        const int nt = (len + 127) / 128;
        gemm_x_kernel<<<BB * nt, 768, 0, stream>>>(inputs, eWih, psi16, 0, t0, len, ct, nt, gbuf);
        enc_scan_kernel<<<BB, 512, 0, stream>>>(gbuf, t0, len, ct, eWhh, ebih, ebhh, henc);
    }
    latent_kernel<<<BB, 256, 0, stream>>>(henc, eps, to_mu, to_ls, W1, b1, W2, b2, psi2, out);
    psi3_kernel<<<(NPSI + 255) / 256, 256, 0, stream>>>(psi2, W3, b3, psi16);
    for (int t0 = 0; t0 < TT; t0 += ct) {
        const int len = (TT - t0 < ct) ? (TT - t0) : ct;
        const int nt = (len + 127) / 128;
        gemm_x_kernel<<<BB * nt, 768, 0, stream>>>(inputs, gWih, psi16, 1, t0, len, ct, nt, gbuf);
        dec_scan_kernel<<<BB, 512, 0, stream>>>(gbuf, t0, len, ct, state, gWhh, gbias, psi16,
                                                dcarry, hseq, out);
    }
    yhat_kernel<<<BB * 32, 256, 0, stream>>>(hseq, psi16, out);
    post_kernel<<<BB * 8, 256, 0, stream>>>(inputs, psi16, out);
}